// Round 10
// baseline (281.190 us; speedup 1.0000x reference)
//
#include <hip/hip_runtime.h>
#include <hip/hip_bf16.h>
#include <cstdint>

#define BATCH 16
#define ATTRS 84
#define NC    80
#define HH    160
#define WW    160
#define HWSZ  (HH * WW)      // 25600
#define KTOP  100
#define CAP   8192
#define XGATE 2.9444389791664403f   // logit(0.95): sigmoid(x)>=0.95 <=> x>=XGATE
#define LCAP  192            // per-WG candidate buffer (expected ~26/WG)
#define CSTR  16             // counts stride (u32) -> one cacheline per counter
#define CHUNKS 125           // 80*25600 floats = 125 chunks * 4096 float4

__device__ __forceinline__ float sigf(float x) {
    return 1.0f / (1.0f + __expf(-x));
}

// ---------------------------------------------------------------------------
// Kernel 1: streaming gate-first NMS. No LDS tile, no halos.
// Each WG scans 4096 contiguous float4 of one batch's class slab (lane-
// contiguous -> perfect coalescing). Gate passes ~0.16%; survivors do a
// 25-load global window probe (L3-resident input) + exact max test.
// Survivors buffered in tiny LDS, one global atomic per WG.
// ---------------------------------------------------------------------------
__global__ __launch_bounds__(256) void k_nms(const float* __restrict__ in,
                                             unsigned long long* __restrict__ gather,
                                             unsigned int* __restrict__ counts) {
    const int wg    = blockIdx.x;         // b*CHUNKS + chunk
    const int b     = wg / CHUNKS;
    const int chunk = wg % CHUNKS;
    const int t     = (int)threadIdx.x;

    __shared__ unsigned long long lbuf[LCAP];
    __shared__ unsigned int lcount;
    __shared__ unsigned int gbase;

    if (t == 0) lcount = 0;
    __syncthreads();

    const float* slab = in + ((size_t)b * ATTRS + 4) * HWSZ;  // 80*25600 floats
    const int base_f4 = chunk * 4096;

#pragma unroll
    for (int it = 0; it < 16; ++it) {
        const int f4 = base_f4 + it * 256 + t;
        const float4 v = *reinterpret_cast<const float4*>(slab + (size_t)f4 * 4);
        const float vmax = fmaxf(fmaxf(v.x, v.y), fmaxf(v.z, v.w));
        if (vmax >= XGATE) {              // rare: ~1 in 150 float4s
#pragma unroll
            for (int jj = 0; jj < 4; ++jj) {
                const float x = (&v.x)[jj];
                if (x >= XGATE) {
                    const int f = f4 * 4 + jj;
                    const int c = f / HWSZ;
                    const int r = f % HWSZ;
                    const int h = r / WW;
                    const int w = r % WW;
                    // 5x5 window over (w, c), h fixed; OOB w -> skip (=-inf),
                    // c clamped (duplicates harmless under max)
                    const int c0 = max(c - 2, 0), c1 = min(c + 2, NC - 1);
                    const int wl = max(w - 2, 0), wh = min(w + 2, WW - 1);
                    float vm = -INFINITY;
                    for (int cc = c0; cc <= c1; ++cc) {
                        const float* rowp = slab + (size_t)cc * HWSZ + h * WW;
                        for (int ww = wl; ww <= wh; ++ww) {
                            vm = fmaxf(vm, rowp[ww]);
                        }
                    }
                    if (x == vm) {
                        const float ssc = sigf(x);
                        unsigned long long key =
                            ((unsigned long long)__float_as_uint(ssc) << 21) |
                            (unsigned long long)(0x1FFFFFu - (unsigned)f);  // score desc, idx asc
                        unsigned p = atomicAdd(&lcount, 1u);
                        if (p < LCAP) {
                            lbuf[p] = key;
                        } else {  // statistically unreachable; exactness fallback
                            unsigned g = atomicAdd(&counts[b * CSTR], 1u);
                            if (g < CAP) gather[(size_t)b * CAP + g] = key;
                        }
                    }
                }
            }
        }
    }
    __syncthreads();

    // ---- Flush: one global atomic per WG, coalesced bulk copy ----
    const unsigned n = min(lcount, (unsigned)LCAP);
    if (t == 0 && n > 0) gbase = atomicAdd(&counts[b * CSTR], n);
    __syncthreads();
    for (unsigned i = t; i < n; i += 256) {
        unsigned g = gbase + i;
        if (g < CAP) gather[(size_t)b * CAP + g] = lbuf[i];
    }
}

// ---------------------------------------------------------------------------
// Kernel 2: per-batch exact top-100 selection from gathered candidates.
// ---------------------------------------------------------------------------
__global__ __launch_bounds__(256) void k_select(const unsigned long long* __restrict__ gather,
                                                const unsigned int* __restrict__ counts,
                                                unsigned int* __restrict__ picks) {
    const int b = blockIdx.x;
    const int t = (int)threadIdx.x;

    __shared__ unsigned int hist[2048];       // 8 KB
    __shared__ unsigned int chunksum[256];
    __shared__ unsigned long long compact[512];
    __shared__ unsigned int ncompact;
    __shared__ int b2_sh;

    const int M = min(counts[b * CSTR], (unsigned)CAP);
    const unsigned long long* keys = gather + (size_t)b * CAP;

    for (int i = t; i < 2048; i += 256) hist[i] = 0;
    if (t == 0) ncompact = 0;
    __syncthreads();

    for (int i = t; i < M; i += 256) {
        unsigned sb = (unsigned)(keys[i] >> 21);
        int bk = (int)((sb - 0x3F700000u) >> 9);
        bk = min(max(bk, 0), 2047);
        atomicAdd(&hist[bk], 1u);
    }
    __syncthreads();

    unsigned sum = 0;
#pragma unroll
    for (int j = 0; j < 8; ++j) sum += hist[t * 8 + j];
    chunksum[t] = sum;
    __syncthreads();
    for (int off = 1; off < 256; off <<= 1) {
        unsigned v = (t + off < 256) ? chunksum[t + off] : 0u;
        __syncthreads();
        chunksum[t] += v;
        __syncthreads();
    }

    const int target = (M < KTOP) ? M : KTOP;
    if (target > 0 &&
        (int)chunksum[t] >= target && (t == 255 || (int)chunksum[t + 1] < target)) {
        unsigned cum = (t == 255) ? 0u : chunksum[t + 1];
        int bsel = t * 8;
        for (int j = 7; j >= 0; --j) {
            cum += hist[t * 8 + j];
            if ((int)cum >= target) { bsel = t * 8 + j; break; }
        }
        b2_sh = bsel;
    }
    __syncthreads();
    const int b2 = b2_sh;

    for (int i = t; i < M; i += 256) {
        unsigned long long k = keys[i];
        unsigned sb = (unsigned)(k >> 21);
        int bk = min(max((int)((sb - 0x3F700000u) >> 9), 0), 2047);
        if (bk >= b2) {
            unsigned p = atomicAdd(&ncompact, 1u);
            if (p < 512) compact[p] = k;
        }
    }
    __syncthreads();

    const int N = (int)min(ncompact, 512u);
    for (int i = t; i < N; i += 256) {
        unsigned long long ki = compact[i];
        int rank = 0;
        for (int j = 0; j < N; ++j) rank += (compact[j] > ki) ? 1 : 0;
        if (rank < KTOP) {
            unsigned idx = 0x1FFFFFu - (unsigned)(ki & 0x1FFFFFu);
            picks[b * KTOP + rank] = idx % HWSZ;   // spatial index
        }
    }
}

// ---------------------------------------------------------------------------
// Kernel 3: one WG per pick. Box decode + suppressed 80-class row.
// ---------------------------------------------------------------------------
__global__ __launch_bounds__(128) void k_emit(const float* __restrict__ in,
                                              const unsigned int* __restrict__ picks,
                                              float* __restrict__ out) {
    const int pk = blockIdx.x;            // b*KTOP + k
    const int b  = pk / KTOP;
    const int t  = (int)threadIdx.x;
    const unsigned hw = picks[pk];
    const int h = (int)(hw / WW), w = (int)(hw % WW);

    __shared__ float tile[NC][5];

    const float* base = in + (size_t)b * ATTRS * HWSZ;

    if (t < NC) {
        const int c = t;
        // aligned 8-float span covering [w-2, w+2] clamped to the row
        int a0 = (max(w - 2, 0)) & ~3;
        a0 = min(a0, WW - 8);
        const float* rp = base + (size_t)(4 + c) * HWSZ + (size_t)h * WW;
        const float4 f0 = *reinterpret_cast<const float4*>(rp + a0);
        const float4 f1 = *reinterpret_cast<const float4*>(rp + a0 + 4);
        float sp[8] = { f0.x, f0.y, f0.z, f0.w, f1.x, f1.y, f1.z, f1.w };
#pragma unroll
        for (int j = 0; j < 5; ++j) {
            const int wc = w + j - 2;
            float vv = -INFINITY;
            if (wc >= 0 && wc < WW) vv = sigf(sp[wc - a0]);
            tile[c][j] = vv;
        }
    }
    __syncthreads();

    float* orow = out + (size_t)pk * (5 + NC);

    if (t < 4) {
        float v = base[(size_t)t * HWSZ + hw];
        float r;
        if (t == 0)      r = (sigf(v) + (float)w) * 8.0f;
        else if (t == 1) r = (sigf(v) + (float)h) * 8.0f;
        else             r = expf(v) * 64.0f;     // exp(.)*SIGAMA*STRIDE
        orow[t] = r;
    }
    if (t == 4) orow[4] = 1.0f;

    if (t < NC) {
        const int c = t;
        const int cl = max(0, c - 2), ch = min(NC - 1, c + 2);
        float m = -INFINITY;
        for (int cc = cl; cc <= ch; ++cc) {
#pragma unroll
            for (int j = 0; j < 5; ++j) m = fmaxf(m, tile[cc][j]);
        }
        float sc = tile[c][2];
        orow[5 + c] = (sc == m) ? sc : 0.0f;
    }
}

// ---------------------------------------------------------------------------
extern "C" void kernel_launch(void* const* d_in, const int* in_sizes, int n_in,
                              void* d_out, int out_size, void* d_ws, size_t ws_size,
                              hipStream_t stream) {
    const float* in = (const float*)d_in[0];
    float* out = (float*)d_out;

    // workspace layout
    unsigned int* counts = (unsigned int*)d_ws;                               // 16 * CSTR u32 (1 KB)
    unsigned int* picks  = (unsigned int*)((char*)d_ws + 1024);               // 1600 u32
    unsigned long long* gather = (unsigned long long*)((char*)d_ws + 8192);   // 16*CAP u64

    hipMemsetAsync(d_ws, 0, 1024, stream);  // zero candidate counters

    k_nms<<<BATCH * CHUNKS, 256, 0, stream>>>(in, gather, counts);
    k_select<<<BATCH, 256, 0, stream>>>(gather, counts, picks);
    k_emit<<<BATCH * KTOP, 128, 0, stream>>>(in, picks, out);
}

// Round 11
// 212.158 us; speedup vs baseline: 1.3254x; 1.3254x over previous
//
#include <hip/hip_runtime.h>
#include <hip/hip_bf16.h>
#include <cstdint>

#define BATCH 16
#define ATTRS 84
#define NC    80
#define HH    160
#define WW    160
#define HWSZ  (HH * WW)      // 25600
#define KTOP  100
#define CAP   8192
#define XGATE 2.9444389791664403f   // logit(0.95): sigmoid(x)>=0.95 <=> x>=XGATE
#define LCAP  192            // per-WG survivor buffer
#define CANDCAP 128          // per-WG gated-candidate list (mean ~26, sd ~5)
#define CSTR  16             // counts stride (u32) -> one cacheline per counter
#define CHUNKS 125           // 80*25600 floats = 125 chunks * 4096 float4

__device__ __forceinline__ float sigf(float x) {
    return 1.0f / (1.0f + __expf(-x));
}

// Probe one gated element f (raw-domain 5x5 (W,C) window max via clamped
// indices - duplicates harmless under max, identical to -inf padding) and
// push its key if it is the window max.
__device__ __forceinline__ void probe_emit(const float* __restrict__ slab, int f, int b,
                                           unsigned long long* __restrict__ gather,
                                           unsigned int* __restrict__ counts,
                                           unsigned long long* lbuf,
                                           unsigned int* lcount) {
    const float x = slab[f];
    const int c = f / HWSZ;
    const int r = f % HWSZ;
    const int h = r / WW;
    const int w = r % WW;
    float vm = -INFINITY;
#pragma unroll
    for (int dc = -2; dc <= 2; ++dc) {
        const int cc = min(max(c + dc, 0), NC - 1);
        const float* rowp = slab + (size_t)cc * HWSZ + h * WW;
#pragma unroll
        for (int dw = -2; dw <= 2; ++dw) {
            const int ww = min(max(w + dw, 0), WW - 1);
            vm = fmaxf(vm, rowp[ww]);
        }
    }
    if (x == vm) {
        const float ssc = sigf(x);
        unsigned long long key =
            ((unsigned long long)__float_as_uint(ssc) << 21) |
            (unsigned long long)(0x1FFFFFu - (unsigned)f);   // score desc, idx asc
        unsigned p = atomicAdd(lcount, 1u);
        if (p < LCAP) {
            lbuf[p] = key;
        } else {  // statistically unreachable; exactness fallback
            unsigned g = atomicAdd(&counts[b * CSTR], 1u);
            if (g < CAP) gather[(size_t)b * CAP + g] = key;
        }
    }
}

// ---------------------------------------------------------------------------
// Kernel 1: streaming gate-first NMS, two-phase.
// Phase 1 (dense): burst-load 8 float4 to registers (8 outstanding loads/wave),
// gate-test, push gated element indices to an LDS list (no probe inline).
// Phase 2 (sparse, wave-parallel): ~26 candidates/WG processed one-per-lane -
// div/mod + 25-load unrolled window probe with all lanes doing useful work.
// ---------------------------------------------------------------------------
__global__ __launch_bounds__(256) void k_nms(const float* __restrict__ in,
                                             unsigned long long* __restrict__ gather,
                                             unsigned int* __restrict__ counts) {
    const int wg    = blockIdx.x;         // b*CHUNKS + chunk
    const int b     = wg / CHUNKS;
    const int chunk = wg % CHUNKS;
    const int t     = (int)threadIdx.x;

    __shared__ unsigned int cand[CANDCAP];
    __shared__ unsigned int ncand;
    __shared__ unsigned long long lbuf[LCAP];
    __shared__ unsigned int lcount;
    __shared__ unsigned int gbase;

    if (t == 0) { ncand = 0; lcount = 0; }
    __syncthreads();

    const float* slab = in + ((size_t)b * ATTRS + 4) * HWSZ;  // 80*25600 floats
    const int base_f4 = chunk * 4096;

    // ---- Phase 1: dense gate scan, 2 bursts of 8 float4 ----
#pragma unroll
    for (int half = 0; half < 2; ++half) {
        float4 v[8];
#pragma unroll
        for (int k = 0; k < 8; ++k) {
            const int f4 = base_f4 + (half * 8 + k) * 256 + t;
            v[k] = *reinterpret_cast<const float4*>(slab + (size_t)f4 * 4);
        }
#pragma unroll
        for (int k = 0; k < 8; ++k) {
            const float vmax = fmaxf(fmaxf(v[k].x, v[k].y), fmaxf(v[k].z, v[k].w));
            if (vmax >= XGATE) {          // rare: ~1 in 150 float4s
                const int f4 = base_f4 + (half * 8 + k) * 256 + t;
#pragma unroll
                for (int jj = 0; jj < 4; ++jj) {
                    if ((&v[k].x)[jj] >= XGATE) {
                        unsigned p = atomicAdd(&ncand, 1u);
                        if (p < CANDCAP) {
                            cand[p] = (unsigned)(f4 * 4 + jj);
                        } else {  // overflow fallback: inline probe (correct, ~never)
                            probe_emit(slab, f4 * 4 + jj, b, gather, counts, lbuf, &lcount);
                        }
                    }
                }
            }
        }
    }
    __syncthreads();

    // ---- Phase 2: wave-parallel probe of collected candidates ----
    const unsigned nc = min(ncand, (unsigned)CANDCAP);
    for (unsigned i = t; i < nc; i += 256) {
        probe_emit(slab, (int)cand[i], b, gather, counts, lbuf, &lcount);
    }
    __syncthreads();

    // ---- Flush: one global atomic per WG, coalesced bulk copy ----
    const unsigned n = min(lcount, (unsigned)LCAP);
    if (t == 0 && n > 0) gbase = atomicAdd(&counts[b * CSTR], n);
    __syncthreads();
    for (unsigned i = t; i < n; i += 256) {
        unsigned g = gbase + i;
        if (g < CAP) gather[(size_t)b * CAP + g] = lbuf[i];
    }
}

// ---------------------------------------------------------------------------
// Kernel 2: per-batch exact top-100 selection from gathered candidates.
// ---------------------------------------------------------------------------
__global__ __launch_bounds__(256) void k_select(const unsigned long long* __restrict__ gather,
                                                const unsigned int* __restrict__ counts,
                                                unsigned int* __restrict__ picks) {
    const int b = blockIdx.x;
    const int t = (int)threadIdx.x;

    __shared__ unsigned int hist[2048];       // 8 KB
    __shared__ unsigned int chunksum[256];
    __shared__ unsigned long long compact[512];
    __shared__ unsigned int ncompact;
    __shared__ int b2_sh;

    const int M = min(counts[b * CSTR], (unsigned)CAP);
    const unsigned long long* keys = gather + (size_t)b * CAP;

    for (int i = t; i < 2048; i += 256) hist[i] = 0;
    if (t == 0) ncompact = 0;
    __syncthreads();

    for (int i = t; i < M; i += 256) {
        unsigned sb = (unsigned)(keys[i] >> 21);
        int bk = (int)((sb - 0x3F700000u) >> 9);
        bk = min(max(bk, 0), 2047);
        atomicAdd(&hist[bk], 1u);
    }
    __syncthreads();

    unsigned sum = 0;
#pragma unroll
    for (int j = 0; j < 8; ++j) sum += hist[t * 8 + j];
    chunksum[t] = sum;
    __syncthreads();
    for (int off = 1; off < 256; off <<= 1) {
        unsigned v = (t + off < 256) ? chunksum[t + off] : 0u;
        __syncthreads();
        chunksum[t] += v;
        __syncthreads();
    }

    const int target = (M < KTOP) ? M : KTOP;
    if (target > 0 &&
        (int)chunksum[t] >= target && (t == 255 || (int)chunksum[t + 1] < target)) {
        unsigned cum = (t == 255) ? 0u : chunksum[t + 1];
        int bsel = t * 8;
        for (int j = 7; j >= 0; --j) {
            cum += hist[t * 8 + j];
            if ((int)cum >= target) { bsel = t * 8 + j; break; }
        }
        b2_sh = bsel;
    }
    __syncthreads();
    const int b2 = b2_sh;

    for (int i = t; i < M; i += 256) {
        unsigned long long k = keys[i];
        unsigned sb = (unsigned)(k >> 21);
        int bk = min(max((int)((sb - 0x3F700000u) >> 9), 0), 2047);
        if (bk >= b2) {
            unsigned p = atomicAdd(&ncompact, 1u);
            if (p < 512) compact[p] = k;
        }
    }
    __syncthreads();

    const int N = (int)min(ncompact, 512u);
    for (int i = t; i < N; i += 256) {
        unsigned long long ki = compact[i];
        int rank = 0;
        for (int j = 0; j < N; ++j) rank += (compact[j] > ki) ? 1 : 0;
        if (rank < KTOP) {
            unsigned idx = 0x1FFFFFu - (unsigned)(ki & 0x1FFFFFu);
            picks[b * KTOP + rank] = idx % HWSZ;   // spatial index
        }
    }
}

// ---------------------------------------------------------------------------
// Kernel 3: one WG per pick. Box decode + suppressed 80-class row.
// ---------------------------------------------------------------------------
__global__ __launch_bounds__(128) void k_emit(const float* __restrict__ in,
                                              const unsigned int* __restrict__ picks,
                                              float* __restrict__ out) {
    const int pk = blockIdx.x;            // b*KTOP + k
    const int b  = pk / KTOP;
    const int t  = (int)threadIdx.x;
    const unsigned hw = picks[pk];
    const int h = (int)(hw / WW), w = (int)(hw % WW);

    __shared__ float tile[NC][5];

    const float* base = in + (size_t)b * ATTRS * HWSZ;

    if (t < NC) {
        const int c = t;
        // aligned 8-float span covering [w-2, w+2] clamped to the row
        int a0 = (max(w - 2, 0)) & ~3;
        a0 = min(a0, WW - 8);
        const float* rp = base + (size_t)(4 + c) * HWSZ + (size_t)h * WW;
        const float4 f0 = *reinterpret_cast<const float4*>(rp + a0);
        const float4 f1 = *reinterpret_cast<const float4*>(rp + a0 + 4);
        float sp[8] = { f0.x, f0.y, f0.z, f0.w, f1.x, f1.y, f1.z, f1.w };
#pragma unroll
        for (int j = 0; j < 5; ++j) {
            const int wc = w + j - 2;
            float vv = -INFINITY;
            if (wc >= 0 && wc < WW) vv = sigf(sp[wc - a0]);
            tile[c][j] = vv;
        }
    }
    __syncthreads();

    float* orow = out + (size_t)pk * (5 + NC);

    if (t < 4) {
        float v = base[(size_t)t * HWSZ + hw];
        float r;
        if (t == 0)      r = (sigf(v) + (float)w) * 8.0f;
        else if (t == 1) r = (sigf(v) + (float)h) * 8.0f;
        else             r = expf(v) * 64.0f;     // exp(.)*SIGAMA*STRIDE
        orow[t] = r;
    }
    if (t == 4) orow[4] = 1.0f;

    if (t < NC) {
        const int c = t;
        const int cl = max(0, c - 2), ch = min(NC - 1, c + 2);
        float m = -INFINITY;
        for (int cc = cl; cc <= ch; ++cc) {
#pragma unroll
            for (int j = 0; j < 5; ++j) m = fmaxf(m, tile[cc][j]);
        }
        float sc = tile[c][2];
        orow[5 + c] = (sc == m) ? sc : 0.0f;
    }
}

// ---------------------------------------------------------------------------
extern "C" void kernel_launch(void* const* d_in, const int* in_sizes, int n_in,
                              void* d_out, int out_size, void* d_ws, size_t ws_size,
                              hipStream_t stream) {
    const float* in = (const float*)d_in[0];
    float* out = (float*)d_out;

    // workspace layout
    unsigned int* counts = (unsigned int*)d_ws;                               // 16 * CSTR u32 (1 KB)
    unsigned int* picks  = (unsigned int*)((char*)d_ws + 1024);               // 1600 u32
    unsigned long long* gather = (unsigned long long*)((char*)d_ws + 8192);   // 16*CAP u64

    hipMemsetAsync(d_ws, 0, 1024, stream);  // zero candidate counters

    k_nms<<<BATCH * CHUNKS, 256, 0, stream>>>(in, gather, counts);
    k_select<<<BATCH, 256, 0, stream>>>(gather, counts, picks);
    k_emit<<<BATCH * KTOP, 128, 0, stream>>>(in, picks, out);
}